// Round 10
// baseline (385.923 us; speedup 1.0000x reference)
//
#include <hip/hip_runtime.h>
#include <hip/hip_bf16.h>
#include <cstdint>
#include <cstddef>

// Problem dims (fixed)
#define BB 16
#define LL 2048
#define MM (BB * LL)   // 32768 rows
#define KK 1024        // inner dim
#define HH 1024        // hidden per gate

typedef __attribute__((ext_vector_type(8))) short bf16x8;
typedef __attribute__((ext_vector_type(4))) float f32x4;

// ---------- fp32 -> bf16 (RNE) ----------
__device__ __forceinline__ unsigned short f2bf(float f) {
    unsigned u = __builtin_bit_cast(unsigned, f);
    u += 0x7fffu + ((u >> 16) & 1u);
    return (unsigned short)(u >> 16);
}

__global__ void cvt_f32_to_bf16(const float* __restrict__ in,
                                unsigned short* __restrict__ out, int n8) {
    int i = blockIdx.x * blockDim.x + threadIdx.x;
    if (i >= n8) return;
    const float4* p = reinterpret_cast<const float4*>(in) + (size_t)i * 2;
    float4 v0 = p[0];
    float4 v1 = p[1];
    union { unsigned short us[8]; uint4 v; } o;
    o.us[0] = f2bf(v0.x); o.us[1] = f2bf(v0.y);
    o.us[2] = f2bf(v0.z); o.us[3] = f2bf(v0.w);
    o.us[4] = f2bf(v1.x); o.us[5] = f2bf(v1.y);
    o.us[6] = f2bf(v1.z); o.us[7] = f2bf(v1.w);
    reinterpret_cast<uint4*>(out)[i] = o.v;
}

// ---------- mask scan ----------
__global__ __launch_bounds__(1024) void scan_mask(const int* __restrict__ mask,
                                                  int* __restrict__ rows,
                                                  int* __restrict__ Na) {
    __shared__ int psum[1024];
    const int t = threadIdx.x;
    const int base = t * 32;
    int m[32];
    int cnt = 0;
#pragma unroll
    for (int i = 0; i < 32; ++i) { m[i] = mask[base + i]; cnt += (m[i] != 0); }
    psum[t] = cnt;
    __syncthreads();
    for (int off = 1; off < 1024; off <<= 1) {
        int v = (t >= off) ? psum[t - off] : 0;
        __syncthreads();
        psum[t] += v;
        __syncthreads();
    }
    int offset = psum[t] - cnt;
#pragma unroll
    for (int i = 0; i < 32; ++i) {
        if (m[i]) rows[offset++] = base + i;
    }
    if (t == 1023) *Na = psum[1023];
}

// ---------- gather active rows of x, f32 -> bf16 ----------
__global__ __launch_bounds__(256) void gather_cvt(const float* __restrict__ x,
                                                  const int* __restrict__ rows,
                                                  const int* __restrict__ Na,
                                                  unsigned short* __restrict__ xbf) {
    const int j = blockIdx.x;
    if (j >= *Na) return;
    const int r = rows[j];
    const float4 v = reinterpret_cast<const float4*>(x + (size_t)r * KK)[threadIdx.x];
    ushort4 o;
    o.x = f2bf(v.x); o.y = f2bf(v.y); o.z = f2bf(v.z); o.w = f2bf(v.w);
    reinterpret_cast<ushort4*>(xbf + (size_t)j * KK)[threadIdx.x] = o;
}

// ---------- exact zeros for masked-out output rows ----------
__global__ __launch_bounds__(256) void zero_masked(const int* __restrict__ mask,
                                                   float* __restrict__ out) {
    const int m = blockIdx.x;
    if (mask[m] != 0) return;
    const int bb = m >> 11;
    const int ll = m & 2047;
    float4 z = {0.f, 0.f, 0.f, 0.f};
    reinterpret_cast<float4*>(out + ((size_t)ll * BB + bb) * HH)[threadIdx.x] = z;
}

// ---------- async global->LDS, 16B per lane ----------
__device__ __forceinline__ void gload16(const unsigned short* g, unsigned short* l) {
    __builtin_amdgcn_global_load_lds(
        (const __attribute__((address_space(1))) unsigned int*)g,
        (__attribute__((address_space(3))) unsigned int*)l,
        16, 0, 0);
}

#define WAITVM0  asm volatile("s_waitcnt vmcnt(0)" ::: "memory")
#define SB       __builtin_amdgcn_sched_barrier(0)
#define BAR      __builtin_amdgcn_s_barrier()

// ---------- fused GEMM + GRU gating: R6 skeleton, low-acc / high-occupancy ----------
// BM=128, BN=32 x 3 gates, BK=32, 256 threads (4 waves, 2M x 2N).
// Per-wave output 64 rows x 16 cols x 3 gates -> acc = 48 VGPRs (vs 96 at BN=64).
// Target: total regs <= 128/wave -> 4 waves/SIMD, 16 waves/CU (2x R6's TLP) —
// occupancy, not pipeline depth, was shown binding (R5/R7/R9 all lost to R6).
// LDS: 2 buffers x 8192 shorts (16KB) = 32KB/block -> 4 blocks/CU (128KB).
// Buffer layout (shorts): A rows 0-127 at [0,4096); B region [4096,8192):
//   B0 rows 0-31, B1 rows 32-63, B2 rows 64-95, junk 96-127 (gload 64-row
//   granularity: 4th call half-duplicates B2 -> +2KB/tile L2 traffic, harmless).
// Swizzle (64B rows, 4 slots of 16B): slot s of row r holds chunk s^((r>>1)&3);
// verified conflict-free in R7/R8 (SQ_LDS_BANK_CONFLICT = 0). Staged via linear
// gload dest + inverse-swizzled global source (rule #21).
template <int MODE>
__global__ __launch_bounds__(256, 4) void gru_layer(
    const unsigned short* __restrict__ A,
    const unsigned short* __restrict__ W,
    const float* __restrict__ b_ih,
    const float* __restrict__ b_hh,
    const int* __restrict__ rows,
    const int* __restrict__ Na_p,
    unsigned short* __restrict__ out_bf,
    float* __restrict__ out_f) {
    __shared__ unsigned short lds[2][8192];  // 32768 B

    const int Na = *Na_p;
    const int m0 = blockIdx.x * 128;
    if (m0 >= Na) return;
    const int n0 = blockIdx.y * 32;

    const int tid  = threadIdx.x;
    const int lane = tid & 63;
    const int wid  = tid >> 6;
    const int wr   = wid >> 1;  // 0..1 (64 rows each)
    const int wc   = wid & 1;   // 0..1 (16 cols each)

    // --- staging: thread t covers row t>>2 (0..63 per call), slot t&3 ---
    const int trow = tid >> 2;
    const int tcol = ((tid & 3) ^ ((trow >> 1) & 3)) * 8;    // inverse-swizzled k
    int r0 = m0 + trow;        if (r0 >= Na) r0 = Na - 1;
    int r1 = m0 + 64 + trow;   if (r1 >= Na) r1 = Na - 1;
    const unsigned short* aA = A + (size_t)r0 * KK + tcol;        // A rows 0-63
    const unsigned short* aB = A + (size_t)r1 * KK + tcol;        // A rows 64-127
    // B0+B1 in one call: trow<32 -> gate0 row trow; else gate1 row trow-32
    const int b01row = (trow < 32) ? (0 * HH + n0 + trow) : (1 * HH + n0 + trow - 32);
    const unsigned short* b01 = W + (size_t)b01row * KK + tcol;
    // B2 + duplicate: row = gate2 row (trow & 31)
    const unsigned short* b2d = W + (size_t)(2 * HH + n0 + (trow & 31)) * KK + tcol;

#define STAGE(kt, buf) do {                                   \
        const int _o = (kt) * 32;                             \
        unsigned short* D = &lds[(buf)][wid * 512];           \
        gload16(aA  + _o, D + 0);                             \
        gload16(aB  + _o, D + 2048);                          \
        gload16(b01 + _o, D + 4096);                          \
        gload16(b2d + _o, D + 6144);                          \
    } while (0)

    // --- read offsets: lane l, row base+l15, chunk c=l>>4 at slot c^((row>>1)&3);
    //     all row bases are multiples of 16 -> (row>>1)&3 == (l15>>1)&3.
    const int l15 = lane & 15;
    const int akp = (((lane >> 4) ^ (lane >> 1)) & 3) << 3;   // shorts
    int aoff[4], boff[3];
#pragma unroll
    for (int mf = 0; mf < 4; ++mf)
        aoff[mf] = (wr * 64 + mf * 16 + l15) * 32 + akp;
#pragma unroll
    for (int g = 0; g < 3; ++g)
        boff[g] = 4096 + (g * 32 + wc * 16 + l15) * 32 + akp;

    f32x4 acc[4][3] = {};   // 48 regs

#define COMPUTE(Lp) do {                                                          \
        bf16x8 af[4], bf[3];                                                      \
        _Pragma("unroll") for (int mf = 0; mf < 4; ++mf)                          \
            af[mf] = *reinterpret_cast<const bf16x8*>(&(Lp)[aoff[mf]]);           \
        _Pragma("unroll") for (int g = 0; g < 3; ++g)                             \
            bf[g] = *reinterpret_cast<const bf16x8*>(&(Lp)[boff[g]]);             \
        __builtin_amdgcn_s_setprio(1);                                            \
        _Pragma("unroll") for (int g = 0; g < 3; ++g)                             \
            _Pragma("unroll") for (int mf = 0; mf < 4; ++mf)                      \
                acc[mf][g] = __builtin_amdgcn_mfma_f32_16x16x32_bf16(             \
                    af[mf], bf[g], acc[mf][g], 0, 0, 0);                          \
        __builtin_amdgcn_s_setprio(0);                                            \
    } while (0)

    // prologue: stage tile 0, drain, barrier
    STAGE(0, 0);
    WAITVM0; BAR; SB;

    int cur = 0;
#pragma unroll 1
    for (int kt = 0; kt < 31; ++kt) {
        STAGE(kt + 1, cur ^ 1);          // issue next-tile loads FIRST
        const unsigned short* L = &lds[cur][0];
        COMPUTE(L);                       // reads + 12 MFMA hide the latency
        WAITVM0; BAR; SB;                 // drain after compute, once per tile
        cur ^= 1;
    }
    {   // peeled last tile: no staging
        const unsigned short* L = &lds[cur][0];
        COMPUTE(L);
    }

    // --- epilogue: gating; C/D layout col = lane&15, row = (lane>>4)*4 + j ---
    const int col = n0 + wc * 16 + l15;
    const float br_b = b_ih[col] + b_hh[col];
    const float bz_b = b_ih[HH + col] + b_hh[HH + col];
    const float bn_i = b_ih[2 * HH + col];
    const float bn_h = b_hh[2 * HH + col];
#pragma unroll
    for (int mf = 0; mf < 4; ++mf) {
#pragma unroll
        for (int j = 0; j < 4; ++j) {
            const int row = m0 + wr * 64 + mf * 16 + (lane >> 4) * 4 + j;
            if (row >= Na) continue;
            const float r = 1.f / (1.f + __expf(-(acc[mf][0][j] + br_b)));
            const float z = 1.f / (1.f + __expf(-(acc[mf][1][j] + bz_b)));
            const float n = tanhf(acc[mf][2][j] + bn_i + r * bn_h);
            const float h = (1.f - z) * n;
            if (MODE == 0) {
                out_bf[(size_t)row * HH + col] = f2bf(h);
            } else {
                const int orig = rows[row];
                const int bb = orig >> 11;
                const int ll = orig & 2047;
                out_f[((size_t)ll * BB + bb) * HH + col] = h;
            }
        }
    }
#undef STAGE
#undef COMPUTE
}

extern "C" void kernel_launch(void* const* d_in, const int* in_sizes, int n_in,
                              void* d_out, int out_size, void* d_ws, size_t ws_size,
                              hipStream_t stream) {
    const float* x   = (const float*)d_in[0];
    const int*   msk = (const int*)d_in[1];
    const float* W0  = (const float*)d_in[2];
    const float* bi0 = (const float*)d_in[4];
    const float* bh0 = (const float*)d_in[5];
    const float* W1  = (const float*)d_in[6];
    const float* bi1 = (const float*)d_in[8];
    const float* bh1 = (const float*)d_in[9];
    float* out = (float*)d_out;

    char* ws = (char*)d_ws;
    unsigned short* xbf  = (unsigned short*)ws;                  // 67,108,864 B (worst case)
    unsigned short* h1bf = (unsigned short*)(ws + 67108864);     // 67,108,864 B (worst case)
    unsigned short* w0bf = (unsigned short*)(ws + 134217728);    //  6,291,456 B
    unsigned short* w1bf = (unsigned short*)(ws + 140509184);    //  6,291,456 B
    int* rows = (int*)(ws + 146800640);                          //    131,072 B
    int* Na   = (int*)(ws + 146931712);                          //          4 B

    scan_mask<<<1, 1024, 0, stream>>>(msk, rows, Na);

    cvt_f32_to_bf16<<<1536, 256, 0, stream>>>(W0, w0bf, 3 * HH * KK / 8);
    cvt_f32_to_bf16<<<1536, 256, 0, stream>>>(W1, w1bf, 3 * HH * KK / 8);

    zero_masked<<<MM, 256, 0, stream>>>(msk, out);
    gather_cvt<<<MM, 256, 0, stream>>>(x, rows, Na, xbf);

    dim3 grid(MM / 128, HH / 32);  // (256, 32) worst case; blocks past Na exit
    gru_layer<0><<<grid, 256, 0, stream>>>(xbf, w0bf, bi0, bh0, rows, Na, h1bf, nullptr);
    gru_layer<1><<<grid, 256, 0, stream>>>(h1bf, w1bf, bi1, bh1, rows, Na, nullptr, out);
}

// Round 11
// 370.246 us; speedup vs baseline: 1.0423x; 1.0423x over previous
//
#include <hip/hip_runtime.h>
#include <hip/hip_bf16.h>
#include <cstdint>
#include <cstddef>

// Problem dims (fixed)
#define BB 16
#define LL 2048
#define MM (BB * LL)   // 32768 rows
#define KK 1024        // inner dim
#define HH 1024        // hidden per gate

typedef __attribute__((ext_vector_type(8))) short bf16x8;
typedef __attribute__((ext_vector_type(4))) float f32x4;

// ---------- fp32 -> bf16 (RNE) ----------
__device__ __forceinline__ unsigned short f2bf(float f) {
    unsigned u = __builtin_bit_cast(unsigned, f);
    u += 0x7fffu + ((u >> 16) & 1u);
    return (unsigned short)(u >> 16);
}

__global__ void cvt_f32_to_bf16(const float* __restrict__ in,
                                unsigned short* __restrict__ out, int n8) {
    int i = blockIdx.x * blockDim.x + threadIdx.x;
    if (i >= n8) return;
    const float4* p = reinterpret_cast<const float4*>(in) + (size_t)i * 2;
    float4 v0 = p[0];
    float4 v1 = p[1];
    union { unsigned short us[8]; uint4 v; } o;
    o.us[0] = f2bf(v0.x); o.us[1] = f2bf(v0.y);
    o.us[2] = f2bf(v0.z); o.us[3] = f2bf(v0.w);
    o.us[4] = f2bf(v1.x); o.us[5] = f2bf(v1.y);
    o.us[6] = f2bf(v1.z); o.us[7] = f2bf(v1.w);
    reinterpret_cast<uint4*>(out)[i] = o.v;
}

// ---------- mask scan ----------
__global__ __launch_bounds__(1024) void scan_mask(const int* __restrict__ mask,
                                                  int* __restrict__ rows,
                                                  int* __restrict__ Na) {
    __shared__ int psum[1024];
    const int t = threadIdx.x;
    const int base = t * 32;
    int m[32];
    int cnt = 0;
#pragma unroll
    for (int i = 0; i < 32; ++i) { m[i] = mask[base + i]; cnt += (m[i] != 0); }
    psum[t] = cnt;
    __syncthreads();
    for (int off = 1; off < 1024; off <<= 1) {
        int v = (t >= off) ? psum[t - off] : 0;
        __syncthreads();
        psum[t] += v;
        __syncthreads();
    }
    int offset = psum[t] - cnt;
#pragma unroll
    for (int i = 0; i < 32; ++i) {
        if (m[i]) rows[offset++] = base + i;
    }
    if (t == 1023) *Na = psum[1023];
}

// ---------- gather active rows of x, f32 -> bf16 ----------
__global__ __launch_bounds__(256) void gather_cvt(const float* __restrict__ x,
                                                  const int* __restrict__ rows,
                                                  const int* __restrict__ Na,
                                                  unsigned short* __restrict__ xbf) {
    const int j = blockIdx.x;
    if (j >= *Na) return;
    const int r = rows[j];
    const float4 v = reinterpret_cast<const float4*>(x + (size_t)r * KK)[threadIdx.x];
    ushort4 o;
    o.x = f2bf(v.x); o.y = f2bf(v.y); o.z = f2bf(v.z); o.w = f2bf(v.w);
    reinterpret_cast<ushort4*>(xbf + (size_t)j * KK)[threadIdx.x] = o;
}

// ---------- exact zeros for masked-out output rows ----------
__global__ __launch_bounds__(256) void zero_masked(const int* __restrict__ mask,
                                                   float* __restrict__ out) {
    const int m = blockIdx.x;
    if (mask[m] != 0) return;
    const int bb = m >> 11;
    const int ll = m & 2047;
    float4 z = {0.f, 0.f, 0.f, 0.f};
    reinterpret_cast<float4*>(out + ((size_t)ll * BB + bb) * HH)[threadIdx.x] = z;
}

// ---------- async global->LDS, 16B per lane ----------
__device__ __forceinline__ void gload16(const unsigned short* g, unsigned short* l) {
    __builtin_amdgcn_global_load_lds(
        (const __attribute__((address_space(1))) unsigned int*)g,
        (__attribute__((address_space(3))) unsigned int*)l,
        16, 0, 0);
}

#define WAITVM5  asm volatile("s_waitcnt vmcnt(5)" ::: "memory")
#define WAITVM0  asm volatile("s_waitcnt vmcnt(0)" ::: "memory")
#define SB       __builtin_amdgcn_sched_barrier(0)
#define BAR      __builtin_amdgcn_s_barrier()

// ---------- fused GEMM + GRU gating: 3-buffer ring, 2-tile lead, 1 barrier/tile ----------
// BM=128, BN=64 x 3 gates, BK=32, 256 threads (4 waves, 2M x 2N).
// Ring of 3 buffers x 10240 shorts (20KB) = 60KB LDS -> 2 blocks/CU (VGPR-capped
// anyway: acc=96 AGPR + ~80 arch = ~176/wave -> 2 waves/SIMD; R10 proved MORE
// occupancy at smaller tiles loses, R5/R7 proved more barriers lose).
// Swizzle (64B rows, 4 slots of 16B): slot s of row r holds chunk s^((r>>1)&3);
// verified conflict-free (R7/R8: SQ_LDS_BANK_CONFLICT = 0). Linear gload dest +
// inverse-swizzled global source (rule #21).
// Schedule per tile kt: vmcnt(5) -> BAR -> STAGE(kt+2 -> buf[(kt+2)%3]) ->
// COMPUTE(buf[kt%3]). The wait confirms loads issued TWO tiles (~1200cy) ago
// (free), vs R6's vmcnt(0) on ~250cy-old loads (the measured stall).
// Race audit: STAGE(kt+2) targets the buffer last READ at tile kt-1; every
// wave's tile-(kt-1) ds_reads completed before it reached BAR(kt) (compiler
// lgkm waits precede its MFMAs, which precede the barrier), and the writes
// are issued after BAR(kt) -> WAR closed with a single barrier. Ledger:
// steady outstanding = {kt,kt+1} = 10 loads/wave; peel drains 5 -> 0.
template <int MODE>
__global__ __launch_bounds__(256, 2) void gru_layer(
    const unsigned short* __restrict__ A,
    const unsigned short* __restrict__ W,
    const float* __restrict__ b_ih,
    const float* __restrict__ b_hh,
    const int* __restrict__ rows,
    const int* __restrict__ Na_p,
    unsigned short* __restrict__ out_bf,
    float* __restrict__ out_f) {
    __shared__ unsigned short lds[3][10240];  // 61440 B

    const int Na = *Na_p;
    const int m0 = blockIdx.x * 128;
    if (m0 >= Na) return;
    const int n0 = blockIdx.y * 64;

    const int tid  = threadIdx.x;
    const int lane = tid & 63;
    const int wid  = tid >> 6;
    const int wr   = wid >> 1;  // 0..1
    const int wc   = wid & 1;   // 0..1

    // --- staging: thread t covers row t>>2 (0..63 per unit), slot t&3 ---
    const int trow = tid >> 2;
    const int tcol = ((tid & 3) ^ ((trow >> 1) & 3)) * 8;    // inverse-swizzled k
    int r0 = m0 + trow;        if (r0 >= Na) r0 = Na - 1;
    int r1 = m0 + 64 + trow;   if (r1 >= Na) r1 = Na - 1;
    const unsigned short* a0 = A + (size_t)r0 * KK + tcol;
    const unsigned short* a1 = A + (size_t)r1 * KK + tcol;
    const unsigned short* b0 = W + (size_t)(0 * HH + n0 + trow) * KK + tcol;
    const unsigned short* b1 = W + (size_t)(1 * HH + n0 + trow) * KK + tcol;
    const unsigned short* b2 = W + (size_t)(2 * HH + n0 + trow) * KK + tcol;

#define STAGE(kt, Lb) do {                                       \
        const int _o = (kt) * 32;                                \
        unsigned short* _L = (Lb) + wid * 512;                   \
        gload16(a0 + _o, _L + 0 * 2048);                         \
        gload16(a1 + _o, _L + 1 * 2048);                         \
        gload16(b0 + _o, _L + 2 * 2048);                         \
        gload16(b1 + _o, _L + 3 * 2048);                         \
        gload16(b2 + _o, _L + 4 * 2048);                         \
    } while (0)

    // --- read offsets: lane l, row base+l15, chunk c=l>>4 at slot c^((row>>1)&3);
    //     row bases are multiples of 16 -> (row>>1)&3 == (l15>>1)&3.
    const int l15 = lane & 15;
    const int akp = (((lane >> 4) ^ (lane >> 1)) & 3) << 3;   // shorts
    int aoff[4], boff[2];
#pragma unroll
    for (int mf = 0; mf < 4; ++mf)
        aoff[mf] = (wr * 64 + mf * 16 + l15) * 32 + akp;
#pragma unroll
    for (int nf = 0; nf < 2; ++nf)
        boff[nf] = 4096 + (wc * 32 + nf * 16 + l15) * 32 + akp;

    f32x4 accr[4][2] = {};
    f32x4 accz[4][2] = {};
    f32x4 accn[4][2] = {};

#define COMPUTE(Lp) do {                                                          \
        bf16x8 af[4];                                                             \
        _Pragma("unroll") for (int mf = 0; mf < 4; ++mf)                          \
            af[mf] = *reinterpret_cast<const bf16x8*>(&(Lp)[aoff[mf]]);           \
        _Pragma("unroll") for (int nf = 0; nf < 2; ++nf) {                        \
            bf16x8 br  = *reinterpret_cast<const bf16x8*>(&(Lp)[boff[nf]]);       \
            bf16x8 bz  = *reinterpret_cast<const bf16x8*>(&(Lp)[boff[nf] + 2048]);\
            bf16x8 bnn = *reinterpret_cast<const bf16x8*>(&(Lp)[boff[nf] + 4096]);\
            __builtin_amdgcn_s_setprio(1);                                        \
            _Pragma("unroll") for (int mf = 0; mf < 4; ++mf) {                    \
                accr[mf][nf] = __builtin_amdgcn_mfma_f32_16x16x32_bf16(           \
                    af[mf], br,  accr[mf][nf], 0, 0, 0);                          \
                accz[mf][nf] = __builtin_amdgcn_mfma_f32_16x16x32_bf16(           \
                    af[mf], bz,  accz[mf][nf], 0, 0, 0);                          \
                accn[mf][nf] = __builtin_amdgcn_mfma_f32_16x16x32_bf16(           \
                    af[mf], bnn, accn[mf][nf], 0, 0, 0);                          \
            }                                                                     \
            __builtin_amdgcn_s_setprio(0);                                        \
        }                                                                         \
    } while (0)

    // one ring step, static buffer indices (cb = kt%3, sb = (kt+2)%3)
#define TILE(kt, cb, sb) do {                                  \
        WAITVM5; BAR; SB;                                      \
        STAGE((kt) + 2, &lds[(sb)][0]);                        \
        COMPUTE((&lds[(cb)][0]));                              \
    } while (0)

    // prologue: stage tiles 0,1 (10 loads/wave outstanding)
    STAGE(0, &lds[0][0]);
    STAGE(1, &lds[1][0]);

#pragma unroll 1
    for (int kt3 = 0; kt3 < 30; kt3 += 3) {
        TILE(kt3 + 0, 0, 2);
        TILE(kt3 + 1, 1, 0);
        TILE(kt3 + 2, 2, 1);
    }
    // peel: tiles 30, 31 (no more staging)
    WAITVM5; BAR; SB;
    COMPUTE((&lds[0][0]));   // 30 % 3 == 0
    WAITVM0; BAR; SB;
    COMPUTE((&lds[1][0]));   // 31 % 3 == 1

    // --- epilogue: gating; C/D layout col = lane&15, row = (lane>>4)*4 + j ---
#pragma unroll
    for (int nf = 0; nf < 2; ++nf) {
        const int col = n0 + wc * 32 + nf * 16 + l15;
        const float br_b = b_ih[col] + b_hh[col];
        const float bz_b = b_ih[HH + col] + b_hh[HH + col];
        const float bn_i = b_ih[2 * HH + col];
        const float bn_h = b_hh[2 * HH + col];
#pragma unroll
        for (int mf = 0; mf < 4; ++mf) {
#pragma unroll
            for (int j = 0; j < 4; ++j) {
                const int row = m0 + wr * 64 + mf * 16 + (lane >> 4) * 4 + j;
                if (row >= Na) continue;
                const float r = 1.f / (1.f + __expf(-(accr[mf][nf][j] + br_b)));
                const float z = 1.f / (1.f + __expf(-(accz[mf][nf][j] + bz_b)));
                const float n = tanhf(accn[mf][nf][j] + bn_i + r * bn_h);
                const float h = (1.f - z) * n;
                if (MODE == 0) {
                    out_bf[(size_t)row * HH + col] = f2bf(h);
                } else {
                    const int orig = rows[row];
                    const int bb = orig >> 11;
                    const int ll = orig & 2047;
                    out_f[((size_t)ll * BB + bb) * HH + col] = h;
                }
            }
        }
    }
#undef STAGE
#undef COMPUTE
#undef TILE
}

extern "C" void kernel_launch(void* const* d_in, const int* in_sizes, int n_in,
                              void* d_out, int out_size, void* d_ws, size_t ws_size,
                              hipStream_t stream) {
    const float* x   = (const float*)d_in[0];
    const int*   msk = (const int*)d_in[1];
    const float* W0  = (const float*)d_in[2];
    const float* bi0 = (const float*)d_in[4];
    const float* bh0 = (const float*)d_in[5];
    const float* W1  = (const float*)d_in[6];
    const float* bi1 = (const float*)d_in[8];
    const float* bh1 = (const float*)d_in[9];
    float* out = (float*)d_out;

    char* ws = (char*)d_ws;
    unsigned short* xbf  = (unsigned short*)ws;                  // 67,108,864 B (worst case)
    unsigned short* h1bf = (unsigned short*)(ws + 67108864);     // 67,108,864 B (worst case)
    unsigned short* w0bf = (unsigned short*)(ws + 134217728);    //  6,291,456 B
    unsigned short* w1bf = (unsigned short*)(ws + 140509184);    //  6,291,456 B
    int* rows = (int*)(ws + 146800640);                          //    131,072 B
    int* Na   = (int*)(ws + 146931712);                          //          4 B

    scan_mask<<<1, 1024, 0, stream>>>(msk, rows, Na);

    cvt_f32_to_bf16<<<1536, 256, 0, stream>>>(W0, w0bf, 3 * HH * KK / 8);
    cvt_f32_to_bf16<<<1536, 256, 0, stream>>>(W1, w1bf, 3 * HH * KK / 8);

    zero_masked<<<MM, 256, 0, stream>>>(msk, out);
    gather_cvt<<<MM, 256, 0, stream>>>(x, rows, Na, xbf);

    dim3 grid(MM / 128, HH / 64);  // (256, 16) worst case; blocks past Na exit
    gru_layer<0><<<grid, 256, 0, stream>>>(xbf, w0bf, bi0, bh0, rows, Na, h1bf, nullptr);
    gru_layer<1><<<grid, 256, 0, stream>>>(h1bf, w1bf, bi1, bh1, rows, Na, nullptr, out);
}